// Round 3
// baseline (271.068 us; speedup 1.0000x reference)
//
#include <hip/hip_runtime.h>

#define NPIX (128 * 128)
#define CH 64
#define RMID 16
#define KK 9
#define PLANE_B 65536            // bytes per channel plane

typedef float v2f __attribute__((ext_vector_type(2)));

// Fused involution kernel.
// r10: occupancy round. Grid 2048 = 8 bq (XCD pin, L&7) x 8 group-QUARTETS x
// 32 strips; block = 256 = 4 rows x 64 col-pairs; wave = one image row.
// r9 post-mortem: warm dispatch 85.5->52.5us from (256,4) scheduling change
// (VGPR stayed 52 = allocation untouched; busy-cycle count constant ->
// genuine stall reduction). Still 66% stall at 4 waves/SIMD, GRID-limited
// (VGPR=52 permits 8 waves/SIMD but 1024 blocks = 4/CU). This round buys
// TLP: 4 groups/block -> 2048 blocks = 8/CU = 32 waves/CU = 8 waves/SIMD.
// Cost: conv1 duplicated x8 (L2-hit re-reads, same-XCD via bq pin); benefit:
// 2x waves hide the L2/SMEM latency the 4-wave scheduler couldn't.
// Pipeline structure from r8: group-0 taps before conv1, taps prefetched one
// group ahead (static [gi&1]), conv1 octet loads double-buffered, shuffles
// hoisted, wgen+combine fused per-k.
__global__ __launch_bounds__(256, 8) void invol_fused(
    const float* __restrict__ x,
    const float* __restrict__ w1,
    const float* __restrict__ b1,
    const float* __restrict__ prelu_a,
    const float* __restrict__ w2,
    const float* __restrict__ b2,
    float* __restrict__ out)
{
    const int c    = threadIdx.x & 63;    // column-pair id (cols 2c, 2c+1)
    const int rsub = threadIdx.x >> 6;    // row within strip, wave-uniform

    const int L     = blockIdx.x;         // 0..2047
    const int bq    = L & 7;              // batch == XCD pin
    const int qo    = (L >> 3) & 7;       // group-quartet (consecutive per XCD)
    const int strip = L >> 6;             // 0..31 (4 rows)

    const int hq  = 4 * strip + rsub;
    const int p0  = hq * 128 + 2 * c;
    const int pb0 = 4 * p0;

    const float* xb  = x + (size_t)bq * CH * NPIX;
    const char*  xbc = (const char*)xb;

    // ---- border masks / clamped row offsets (needed before tap prefetch) --
    const float rm0 = (hq > 0)   ? 1.f : 0.f;
    const float rm2 = (hq < 127) ? 1.f : 0.f;
    const float mL  = (c > 0)    ? 1.f : 0.f;
    const float mR  = (c < 63)   ? 1.f : 0.f;
    const int   ro0 = (hq > 0)   ? -512 : 0;
    const int   ro2 = (hq < 127) ?  512 : 0;

    // ---- prefetch group 0's 6 taps: latency hides under all of conv1 ----
    v2f tA0[2], tA1[2], tA2[2], tE0[2], tE1[2], tE2[2];
    {
        const char* cp0 = xbc + (size_t)(2 * (4 * qo)) * PLANE_B;
        const char* cp1 = cp0 + PLANE_B;
        tA0[0] = *(const v2f*)(cp0 + (size_t)(pb0 + ro0));
        tA1[0] = *(const v2f*)(cp0 + (size_t)pb0);
        tA2[0] = *(const v2f*)(cp0 + (size_t)(pb0 + ro2));
        tE0[0] = *(const v2f*)(cp1 + (size_t)(pb0 + ro0));
        tE1[0] = *(const v2f*)(cp1 + (size_t)pb0);
        tE2[0] = *(const v2f*)(cp1 + (size_t)(pb0 + ro2));
    }

    // ---- conv1 (pixel-pair layout), octet double-buffered ----
    v2f t2[RMID];
#pragma unroll
    for (int r = 0; r < RMID; ++r) {
        const float b = b1[r];
        t2[r].x = b; t2[r].y = b;
    }
    const float* xp = xb + p0;
    v2f xv[2][8];
#pragma unroll
    for (int k = 0; k < 8; ++k)
        xv[0][k] = *(const v2f*)(xp + (size_t)k * NPIX);
#pragma unroll
    for (int oct = 0; oct < 8; ++oct) {
        const int cb = oct & 1, nb = cb ^ 1;       // constant after unroll
        if (oct < 7) {
#pragma unroll
            for (int k = 0; k < 8; ++k)
                xv[nb][k] = *(const v2f*)(xp + (size_t)((oct + 1) * 8 + k) * NPIX);
        }
#pragma unroll
        for (int k = 0; k < 8; ++k) {
#pragma unroll
            for (int r = 0; r < RMID; ++r) {
                const float w = w1[r * CH + oct * 8 + k];   // uniform -> s_load
                v2f wv; wv.x = w; wv.y = w;
                t2[r] = __builtin_elementwise_fma(wv, xv[cb][k], t2[r]);
            }
        }
    }
    // PReLU: t = max(t,0) + a*min(t,0)
    {
        const float a = prelu_a[0];
        v2f av; av.x = a; av.y = a;
        v2f z;  z.x = 0.f; z.y = 0.f;
#pragma unroll
        for (int r = 0; r < RMID; ++r) {
            const v2f pos = __builtin_elementwise_max(t2[r], z);
            const v2f neg = __builtin_elementwise_min(t2[r], z);
            t2[r] = __builtin_elementwise_fma(av, neg, pos);
        }
    }

    v2f rm0v; rm0v.x = rm0; rm0v.y = rm0;
    v2f rm2v; rm2v.x = rm2; rm2v.y = rm2;

    char* obc = (char*)(out + (size_t)bq * CH * NPIX);

#pragma unroll
    for (int gi = 0; gi < 4; ++gi) {
        const int g   = 4 * qo + gi;               // block-uniform
        const int cur = gi & 1, nxt = cur ^ 1;     // constant after unroll

        // -- row-mask the taps, then shuffle EARLY (lgkm drains under wgen) --
        const v2f A0 = tA0[cur] * rm0v;
        const v2f A1 = tA1[cur];
        const v2f A2 = tA2[cur] * rm2v;
        const v2f E0 = tE0[cur] * rm0v;
        const v2f E1 = tE1[cur];
        const v2f E2 = tE2[cur] * rm2v;

        const float lA0 = __shfl_up(A0.y, 1), rA0 = __shfl_down(A0.x, 1);
        const float lA1 = __shfl_up(A1.y, 1), rA1 = __shfl_down(A1.x, 1);
        const float lA2 = __shfl_up(A2.y, 1), rA2 = __shfl_down(A2.x, 1);
        const float lE0 = __shfl_up(E0.y, 1), rE0 = __shfl_down(E0.x, 1);
        const float lE1 = __shfl_up(E1.y, 1), rE1 = __shfl_down(E1.x, 1);
        const float lE2 = __shfl_up(E2.y, 1), rE2 = __shfl_down(E2.x, 1);

        // -- prefetch NEXT group's taps; latency hides under wgen+combine --
        if (gi < 3) {
            const char* np0 = xbc + (size_t)(2 * (g + 1)) * PLANE_B;
            const char* np1 = np0 + PLANE_B;
            tA0[nxt] = *(const v2f*)(np0 + (size_t)(pb0 + ro0));
            tA1[nxt] = *(const v2f*)(np0 + (size_t)pb0);
            tA2[nxt] = *(const v2f*)(np0 + (size_t)(pb0 + ro2));
            tE0[nxt] = *(const v2f*)(np1 + (size_t)(pb0 + ro0));
            tE1[nxt] = *(const v2f*)(np1 + (size_t)pb0);
            tE2[nxt] = *(const v2f*)(np1 + (size_t)(pb0 + ro2));
        }

        // -- fused weight-gen + combine, per k (no wgp array) --
        v2f oA; oA.x = 0.f; oA.y = 0.f;
        v2f oB = oA;
#pragma unroll
        for (int k = 0; k < KK; ++k) {
            const float* w2r = w2 + (g * KK + k) * RMID;  // uniform -> s_load
            const float bb = b2[g * KK + k];
            v2f acc; acc.x = bb; acc.y = bb;
#pragma unroll
            for (int r = 0; r < RMID; ++r) {
                const float w = w2r[r];
                v2f wv; wv.x = w; wv.y = w;
                acc = __builtin_elementwise_fma(wv, t2[r], acc);
            }
            // column-edge masks on this k's weight
            if (k == 0 || k == 3 || k == 6) acc.x *= mL;   // left tap of px0
            if (k == 2 || k == 5 || k == 8) acc.y *= mR;   // right tap of px1

            // tap selection — all constant-folded after unroll
            const v2f Ar = (k < 3) ? A0 : (k < 6) ? A1 : A2;
            const v2f Er = (k < 3) ? E0 : (k < 6) ? E1 : E2;
            const float lA = (k < 3) ? lA0 : (k < 6) ? lA1 : lA2;
            const float rA = (k < 3) ? rA0 : (k < 6) ? rA1 : rA2;
            const float lE = (k < 3) ? lE0 : (k < 6) ? lE1 : lE2;
            const float rE = (k < 3) ? rE0 : (k < 6) ? rE1 : rE2;

            v2f tpA, tpE;
            if (k % 3 == 0)      { tpA.x = lA;   tpA.y = Ar.x;
                                   tpE.x = lE;   tpE.y = Er.x; }
            else if (k % 3 == 1) { tpA = Ar;     tpE = Er;     }
            else                 { tpA.x = Ar.y; tpA.y = rA;
                                   tpE.x = Er.y; tpE.y = rE;   }
            oA = __builtin_elementwise_fma(acc, tpA, oA);
            oB = __builtin_elementwise_fma(acc, tpE, oB);
        }

        __builtin_nontemporal_store(oA, (v2f*)(obc + (size_t)(2 * g)     * PLANE_B + pb0));
        __builtin_nontemporal_store(oB, (v2f*)(obc + (size_t)(2 * g + 1) * PLANE_B + pb0));
    }
}

extern "C" void kernel_launch(void* const* d_in, const int* in_sizes, int n_in,
                              void* d_out, int out_size, void* d_ws, size_t ws_size,
                              hipStream_t stream)
{
    const float* x  = (const float*)d_in[0];
    const float* w1 = (const float*)d_in[1];
    const float* b1 = (const float*)d_in[2];
    const float* pa = (const float*)d_in[3];
    const float* w2 = (const float*)d_in[4];
    const float* b2 = (const float*)d_in[5];
    float* out = (float*)d_out;

    hipLaunchKernelGGL(invol_fused, dim3(2048), dim3(256), 0, stream,
                       x, w1, b1, pa, w2, b2, out);
}

// Round 4
// 131.972 us; speedup vs baseline: 2.0540x; 2.0540x over previous
//
#include <hip/hip_runtime.h>

#define NPIX (128 * 128)
#define CH 64
#define RMID 16
#define KK 9
#define PLANE_B 65536            // bytes per channel plane

typedef float v2f __attribute__((ext_vector_type(2)));

// Fused involution kernel.
// r11: grid 2048 = 8 bq (XCD pin, L&7) x 8 group-quartets x 32 strips;
// block = 256 = 4 rows x 64 col-pairs; wave = one image row.
// r10 post-mortem: __launch_bounds__(256,8) capped VGPR at 32 (<< ~100 live)
// -> massive scratch spill (WRITE_SIZE 32->121 MB, FETCH 21->49 MB, dispatch
// 52->200us). The TLP lever (8 blocks/CU) was never actually tested.
// r11 decouples: keep grid 2048 + 4 groups/block, but (256,4) — r9 proved
// the allocator lands ~52 VGPR under this bound, and VGPR<=64 permits
// 8 waves/SIMD, which grid 2048 = 8 blocks/CU now supplies.
// Pipeline structure from r8: group-0 taps before conv1, taps prefetched one
// group ahead (static [gi&1]), conv1 octet loads double-buffered, shuffles
// hoisted, wgen+combine fused per-k.
__global__ __launch_bounds__(256, 4) void invol_fused(
    const float* __restrict__ x,
    const float* __restrict__ w1,
    const float* __restrict__ b1,
    const float* __restrict__ prelu_a,
    const float* __restrict__ w2,
    const float* __restrict__ b2,
    float* __restrict__ out)
{
    const int c    = threadIdx.x & 63;    // column-pair id (cols 2c, 2c+1)
    const int rsub = threadIdx.x >> 6;    // row within strip, wave-uniform

    const int L     = blockIdx.x;         // 0..2047
    const int bq    = L & 7;              // batch == XCD pin
    const int qo    = (L >> 3) & 7;       // group-quartet (consecutive per XCD)
    const int strip = L >> 6;             // 0..31 (4 rows)

    const int hq  = 4 * strip + rsub;
    const int p0  = hq * 128 + 2 * c;
    const int pb0 = 4 * p0;

    const float* xb  = x + (size_t)bq * CH * NPIX;
    const char*  xbc = (const char*)xb;

    // ---- border masks / clamped row offsets (needed before tap prefetch) --
    const float rm0 = (hq > 0)   ? 1.f : 0.f;
    const float rm2 = (hq < 127) ? 1.f : 0.f;
    const float mL  = (c > 0)    ? 1.f : 0.f;
    const float mR  = (c < 63)   ? 1.f : 0.f;
    const int   ro0 = (hq > 0)   ? -512 : 0;
    const int   ro2 = (hq < 127) ?  512 : 0;

    // ---- prefetch group 0's 6 taps: latency hides under all of conv1 ----
    v2f tA0[2], tA1[2], tA2[2], tE0[2], tE1[2], tE2[2];
    {
        const char* cp0 = xbc + (size_t)(2 * (4 * qo)) * PLANE_B;
        const char* cp1 = cp0 + PLANE_B;
        tA0[0] = *(const v2f*)(cp0 + (size_t)(pb0 + ro0));
        tA1[0] = *(const v2f*)(cp0 + (size_t)pb0);
        tA2[0] = *(const v2f*)(cp0 + (size_t)(pb0 + ro2));
        tE0[0] = *(const v2f*)(cp1 + (size_t)(pb0 + ro0));
        tE1[0] = *(const v2f*)(cp1 + (size_t)pb0);
        tE2[0] = *(const v2f*)(cp1 + (size_t)(pb0 + ro2));
    }

    // ---- conv1 (pixel-pair layout), octet double-buffered ----
    v2f t2[RMID];
#pragma unroll
    for (int r = 0; r < RMID; ++r) {
        const float b = b1[r];
        t2[r].x = b; t2[r].y = b;
    }
    const float* xp = xb + p0;
    v2f xv[2][8];
#pragma unroll
    for (int k = 0; k < 8; ++k)
        xv[0][k] = *(const v2f*)(xp + (size_t)k * NPIX);
#pragma unroll
    for (int oct = 0; oct < 8; ++oct) {
        const int cb = oct & 1, nb = cb ^ 1;       // constant after unroll
        if (oct < 7) {
#pragma unroll
            for (int k = 0; k < 8; ++k)
                xv[nb][k] = *(const v2f*)(xp + (size_t)((oct + 1) * 8 + k) * NPIX);
        }
#pragma unroll
        for (int k = 0; k < 8; ++k) {
#pragma unroll
            for (int r = 0; r < RMID; ++r) {
                const float w = w1[r * CH + oct * 8 + k];   // uniform -> s_load
                v2f wv; wv.x = w; wv.y = w;
                t2[r] = __builtin_elementwise_fma(wv, xv[cb][k], t2[r]);
            }
        }
    }
    // PReLU: t = max(t,0) + a*min(t,0)
    {
        const float a = prelu_a[0];
        v2f av; av.x = a; av.y = a;
        v2f z;  z.x = 0.f; z.y = 0.f;
#pragma unroll
        for (int r = 0; r < RMID; ++r) {
            const v2f pos = __builtin_elementwise_max(t2[r], z);
            const v2f neg = __builtin_elementwise_min(t2[r], z);
            t2[r] = __builtin_elementwise_fma(av, neg, pos);
        }
    }

    v2f rm0v; rm0v.x = rm0; rm0v.y = rm0;
    v2f rm2v; rm2v.x = rm2; rm2v.y = rm2;

    char* obc = (char*)(out + (size_t)bq * CH * NPIX);

#pragma unroll
    for (int gi = 0; gi < 4; ++gi) {
        const int g   = 4 * qo + gi;               // block-uniform
        const int cur = gi & 1, nxt = cur ^ 1;     // constant after unroll

        // -- row-mask the taps, then shuffle EARLY (lgkm drains under wgen) --
        const v2f A0 = tA0[cur] * rm0v;
        const v2f A1 = tA1[cur];
        const v2f A2 = tA2[cur] * rm2v;
        const v2f E0 = tE0[cur] * rm0v;
        const v2f E1 = tE1[cur];
        const v2f E2 = tE2[cur] * rm2v;

        const float lA0 = __shfl_up(A0.y, 1), rA0 = __shfl_down(A0.x, 1);
        const float lA1 = __shfl_up(A1.y, 1), rA1 = __shfl_down(A1.x, 1);
        const float lA2 = __shfl_up(A2.y, 1), rA2 = __shfl_down(A2.x, 1);
        const float lE0 = __shfl_up(E0.y, 1), rE0 = __shfl_down(E0.x, 1);
        const float lE1 = __shfl_up(E1.y, 1), rE1 = __shfl_down(E1.x, 1);
        const float lE2 = __shfl_up(E2.y, 1), rE2 = __shfl_down(E2.x, 1);

        // -- prefetch NEXT group's taps; latency hides under wgen+combine --
        if (gi < 3) {
            const char* np0 = xbc + (size_t)(2 * (g + 1)) * PLANE_B;
            const char* np1 = np0 + PLANE_B;
            tA0[nxt] = *(const v2f*)(np0 + (size_t)(pb0 + ro0));
            tA1[nxt] = *(const v2f*)(np0 + (size_t)pb0);
            tA2[nxt] = *(const v2f*)(np0 + (size_t)(pb0 + ro2));
            tE0[nxt] = *(const v2f*)(np1 + (size_t)(pb0 + ro0));
            tE1[nxt] = *(const v2f*)(np1 + (size_t)pb0);
            tE2[nxt] = *(const v2f*)(np1 + (size_t)(pb0 + ro2));
        }

        // -- fused weight-gen + combine, per k (no wgp array) --
        v2f oA; oA.x = 0.f; oA.y = 0.f;
        v2f oB = oA;
#pragma unroll
        for (int k = 0; k < KK; ++k) {
            const float* w2r = w2 + (g * KK + k) * RMID;  // uniform -> s_load
            const float bb = b2[g * KK + k];
            v2f acc; acc.x = bb; acc.y = bb;
#pragma unroll
            for (int r = 0; r < RMID; ++r) {
                const float w = w2r[r];
                v2f wv; wv.x = w; wv.y = w;
                acc = __builtin_elementwise_fma(wv, t2[r], acc);
            }
            // column-edge masks on this k's weight
            if (k == 0 || k == 3 || k == 6) acc.x *= mL;   // left tap of px0
            if (k == 2 || k == 5 || k == 8) acc.y *= mR;   // right tap of px1

            // tap selection — all constant-folded after unroll
            const v2f Ar = (k < 3) ? A0 : (k < 6) ? A1 : A2;
            const v2f Er = (k < 3) ? E0 : (k < 6) ? E1 : E2;
            const float lA = (k < 3) ? lA0 : (k < 6) ? lA1 : lA2;
            const float rA = (k < 3) ? rA0 : (k < 6) ? rA1 : rA2;
            const float lE = (k < 3) ? lE0 : (k < 6) ? lE1 : lE2;
            const float rE = (k < 3) ? rE0 : (k < 6) ? rE1 : rE2;

            v2f tpA, tpE;
            if (k % 3 == 0)      { tpA.x = lA;   tpA.y = Ar.x;
                                   tpE.x = lE;   tpE.y = Er.x; }
            else if (k % 3 == 1) { tpA = Ar;     tpE = Er;     }
            else                 { tpA.x = Ar.y; tpA.y = rA;
                                   tpE.x = Er.y; tpE.y = rE;   }
            oA = __builtin_elementwise_fma(acc, tpA, oA);
            oB = __builtin_elementwise_fma(acc, tpE, oB);
        }

        __builtin_nontemporal_store(oA, (v2f*)(obc + (size_t)(2 * g)     * PLANE_B + pb0));
        __builtin_nontemporal_store(oB, (v2f*)(obc + (size_t)(2 * g + 1) * PLANE_B + pb0));
    }
}

extern "C" void kernel_launch(void* const* d_in, const int* in_sizes, int n_in,
                              void* d_out, int out_size, void* d_ws, size_t ws_size,
                              hipStream_t stream)
{
    const float* x  = (const float*)d_in[0];
    const float* w1 = (const float*)d_in[1];
    const float* b1 = (const float*)d_in[2];
    const float* pa = (const float*)d_in[3];
    const float* w2 = (const float*)d_in[4];
    const float* b2 = (const float*)d_in[5];
    float* out = (float*)d_out;

    hipLaunchKernelGGL(invol_fused, dim3(2048), dim3(256), 0, stream,
                       x, w1, b1, pa, w2, b2, out);
}

// Round 5
// 123.682 us; speedup vs baseline: 2.1916x; 1.0670x over previous
//
#include <hip/hip_runtime.h>

#define NPIX (128 * 128)
#define CH 64
#define RMID 16
#define KK 9
#define PLANE_B 65536            // bytes per channel plane

typedef float v2f __attribute__((ext_vector_type(2)));

// sched_barrier mask 0x3CF = ALU|VALU|SALU|MFMA|VMEM-write|DS|DS-r|DS-w may
// cross; VMEM READS may NOT. Pins prefetch loads where the source puts them
// without trapping scalar weight loads or letting the scheduler sink vmem.
#define PIN_VMEM_READS() __builtin_amdgcn_sched_barrier(0x3CF)

// Fused involution kernel.
// r12: back to r9 structure (grid 1024 = 8 bq x 4 octets x 32 strips,
// 8 groups/block, x4 conv1 dup — best known 52.5us) + VMEM-read pinning.
// r11 post-mortem: doubling resident waves (grid 2048) did NOT dilute the
// stall (wall/busy = 2.9x in both configs) -> stall is per-wave serialized
// load latency, not TLP-hideable. Cause: allocator lands at 52 VGPR and the
// pre-RA scheduler sinks every load to its use, so prefetch buffers never
// exist in the emitted code (r8 lesson). Fix: sched_barrier(0x3CF) after
// each prefetch batch — VMEM reads cannot sink past it, forcing loads early
// and their results live across the covering compute (RA must allocate;
// (256,4) permits up to 128 VGPR at unchanged 4 waves/SIMD occupancy).
// Pipeline structure from r8: group-0 taps before conv1, taps prefetched one
// group ahead (static [gi&1]), conv1 octet loads double-buffered, shuffles
// hoisted, wgen+combine fused per-k.
__global__ __launch_bounds__(256, 4) void invol_fused(
    const float* __restrict__ x,
    const float* __restrict__ w1,
    const float* __restrict__ b1,
    const float* __restrict__ prelu_a,
    const float* __restrict__ w2,
    const float* __restrict__ b2,
    float* __restrict__ out)
{
    const int c    = threadIdx.x & 63;    // column-pair id (cols 2c, 2c+1)
    const int rsub = threadIdx.x >> 6;    // row within strip, wave-uniform

    const int L     = blockIdx.x;         // 0..1023
    const int bq    = L & 7;              // batch == XCD pin
    const int go    = (L >> 3) & 3;       // group-octet (consecutive per XCD)
    const int strip = L >> 5;             // 0..31 (4 rows)

    const int hq  = 4 * strip + rsub;
    const int p0  = hq * 128 + 2 * c;
    const int pb0 = 4 * p0;

    const float* xb  = x + (size_t)bq * CH * NPIX;
    const char*  xbc = (const char*)xb;

    // ---- border masks / clamped row offsets (needed before tap prefetch) --
    const float rm0 = (hq > 0)   ? 1.f : 0.f;
    const float rm2 = (hq < 127) ? 1.f : 0.f;
    const float mL  = (c > 0)    ? 1.f : 0.f;
    const float mR  = (c < 63)   ? 1.f : 0.f;
    const int   ro0 = (hq > 0)   ? -512 : 0;
    const int   ro2 = (hq < 127) ?  512 : 0;

    // ---- prefetch group 0's 6 taps: latency hides under all of conv1 ----
    v2f tA0[2], tA1[2], tA2[2], tE0[2], tE1[2], tE2[2];
    {
        const char* cp0 = xbc + (size_t)(2 * (8 * go)) * PLANE_B;
        const char* cp1 = cp0 + PLANE_B;
        tA0[0] = *(const v2f*)(cp0 + (size_t)(pb0 + ro0));
        tA1[0] = *(const v2f*)(cp0 + (size_t)pb0);
        tA2[0] = *(const v2f*)(cp0 + (size_t)(pb0 + ro2));
        tE0[0] = *(const v2f*)(cp1 + (size_t)(pb0 + ro0));
        tE1[0] = *(const v2f*)(cp1 + (size_t)pb0);
        tE2[0] = *(const v2f*)(cp1 + (size_t)(pb0 + ro2));
    }
    PIN_VMEM_READS();     // group-0 taps may not sink into/below conv1

    // ---- conv1 (pixel-pair layout), octet double-buffered ----
    v2f t2[RMID];
#pragma unroll
    for (int r = 0; r < RMID; ++r) {
        const float b = b1[r];
        t2[r].x = b; t2[r].y = b;
    }
    const float* xp = xb + p0;
    v2f xv[2][8];
#pragma unroll
    for (int k = 0; k < 8; ++k)
        xv[0][k] = *(const v2f*)(xp + (size_t)k * NPIX);
    PIN_VMEM_READS();     // first octet batch pinned before the oct loop
#pragma unroll
    for (int oct = 0; oct < 8; ++oct) {
        const int cb = oct & 1, nb = cb ^ 1;       // constant after unroll
        if (oct < 7) {
#pragma unroll
            for (int k = 0; k < 8; ++k)
                xv[nb][k] = *(const v2f*)(xp + (size_t)((oct + 1) * 8 + k) * NPIX);
        }
        PIN_VMEM_READS(); // next-octet loads issue before this octet's FMAs
#pragma unroll
        for (int k = 0; k < 8; ++k) {
#pragma unroll
            for (int r = 0; r < RMID; ++r) {
                const float w = w1[r * CH + oct * 8 + k];   // uniform -> s_load
                v2f wv; wv.x = w; wv.y = w;
                t2[r] = __builtin_elementwise_fma(wv, xv[cb][k], t2[r]);
            }
        }
    }
    // PReLU: t = max(t,0) + a*min(t,0)
    {
        const float a = prelu_a[0];
        v2f av; av.x = a; av.y = a;
        v2f z;  z.x = 0.f; z.y = 0.f;
#pragma unroll
        for (int r = 0; r < RMID; ++r) {
            const v2f pos = __builtin_elementwise_max(t2[r], z);
            const v2f neg = __builtin_elementwise_min(t2[r], z);
            t2[r] = __builtin_elementwise_fma(av, neg, pos);
        }
    }

    v2f rm0v; rm0v.x = rm0; rm0v.y = rm0;
    v2f rm2v; rm2v.x = rm2; rm2v.y = rm2;

    char* obc = (char*)(out + (size_t)bq * CH * NPIX);

#pragma unroll
    for (int gi = 0; gi < 8; ++gi) {
        const int g   = 8 * go + gi;               // block-uniform
        const int cur = gi & 1, nxt = cur ^ 1;     // constant after unroll

        // -- row-mask the taps, then shuffle EARLY (lgkm drains under wgen) --
        const v2f A0 = tA0[cur] * rm0v;
        const v2f A1 = tA1[cur];
        const v2f A2 = tA2[cur] * rm2v;
        const v2f E0 = tE0[cur] * rm0v;
        const v2f E1 = tE1[cur];
        const v2f E2 = tE2[cur] * rm2v;

        const float lA0 = __shfl_up(A0.y, 1), rA0 = __shfl_down(A0.x, 1);
        const float lA1 = __shfl_up(A1.y, 1), rA1 = __shfl_down(A1.x, 1);
        const float lA2 = __shfl_up(A2.y, 1), rA2 = __shfl_down(A2.x, 1);
        const float lE0 = __shfl_up(E0.y, 1), rE0 = __shfl_down(E0.x, 1);
        const float lE1 = __shfl_up(E1.y, 1), rE1 = __shfl_down(E1.x, 1);
        const float lE2 = __shfl_up(E2.y, 1), rE2 = __shfl_down(E2.x, 1);

        // -- prefetch NEXT group's taps; latency hides under wgen+combine --
        if (gi < 7) {
            const char* np0 = xbc + (size_t)(2 * (g + 1)) * PLANE_B;
            const char* np1 = np0 + PLANE_B;
            tA0[nxt] = *(const v2f*)(np0 + (size_t)(pb0 + ro0));
            tA1[nxt] = *(const v2f*)(np0 + (size_t)pb0);
            tA2[nxt] = *(const v2f*)(np0 + (size_t)(pb0 + ro2));
            tE0[nxt] = *(const v2f*)(np1 + (size_t)(pb0 + ro0));
            tE1[nxt] = *(const v2f*)(np1 + (size_t)pb0);
            tE2[nxt] = *(const v2f*)(np1 + (size_t)(pb0 + ro2));
        }
        PIN_VMEM_READS(); // next-group taps pinned above wgen+combine

        // -- fused weight-gen + combine, per k (no wgp array) --
        v2f oA; oA.x = 0.f; oA.y = 0.f;
        v2f oB = oA;
#pragma unroll
        for (int k = 0; k < KK; ++k) {
            const float* w2r = w2 + (g * KK + k) * RMID;  // uniform -> s_load
            const float bb = b2[g * KK + k];
            v2f acc; acc.x = bb; acc.y = bb;
#pragma unroll
            for (int r = 0; r < RMID; ++r) {
                const float w = w2r[r];
                v2f wv; wv.x = w; wv.y = w;
                acc = __builtin_elementwise_fma(wv, t2[r], acc);
            }
            // column-edge masks on this k's weight
            if (k == 0 || k == 3 || k == 6) acc.x *= mL;   // left tap of px0
            if (k == 2 || k == 5 || k == 8) acc.y *= mR;   // right tap of px1

            // tap selection — all constant-folded after unroll
            const v2f Ar = (k < 3) ? A0 : (k < 6) ? A1 : A2;
            const v2f Er = (k < 3) ? E0 : (k < 6) ? E1 : E2;
            const float lA = (k < 3) ? lA0 : (k < 6) ? lA1 : lA2;
            const float rA = (k < 3) ? rA0 : (k < 6) ? rA1 : rA2;
            const float lE = (k < 3) ? lE0 : (k < 6) ? lE1 : lE2;
            const float rE = (k < 3) ? rE0 : (k < 6) ? rE1 : rE2;

            v2f tpA, tpE;
            if (k % 3 == 0)      { tpA.x = lA;   tpA.y = Ar.x;
                                   tpE.x = lE;   tpE.y = Er.x; }
            else if (k % 3 == 1) { tpA = Ar;     tpE = Er;     }
            else                 { tpA.x = Ar.y; tpA.y = rA;
                                   tpE.x = Er.y; tpE.y = rE;   }
            oA = __builtin_elementwise_fma(acc, tpA, oA);
            oB = __builtin_elementwise_fma(acc, tpE, oB);
        }

        __builtin_nontemporal_store(oA, (v2f*)(obc + (size_t)(2 * g)     * PLANE_B + pb0));
        __builtin_nontemporal_store(oB, (v2f*)(obc + (size_t)(2 * g + 1) * PLANE_B + pb0));
    }
}

extern "C" void kernel_launch(void* const* d_in, const int* in_sizes, int n_in,
                              void* d_out, int out_size, void* d_ws, size_t ws_size,
                              hipStream_t stream)
{
    const float* x  = (const float*)d_in[0];
    const float* w1 = (const float*)d_in[1];
    const float* b1 = (const float*)d_in[2];
    const float* pa = (const float*)d_in[3];
    const float* w2 = (const float*)d_in[4];
    const float* b2 = (const float*)d_in[5];
    float* out = (float*)d_out;

    hipLaunchKernelGGL(invol_fused, dim3(1024), dim3(256), 0, stream,
                       x, w1, b1, pa, w2, b2, out);
}